// Round 14
// baseline (262.798 us; speedup 1.0000x reference)
//
#include <hip/hip_runtime.h>

typedef float f32x4 __attribute__((ext_vector_type(4)));
typedef int   i32x4 __attribute__((ext_vector_type(4)));

namespace {
constexpr int   B_    = 2;
constexpr int   N_    = 250000;
constexpr int   C_    = 64;
constexpr int   NX_   = 1024;
constexpr int   NY_   = 1024;
constexpr int   CELLS = NX_ * NY_;          // 1<<20
constexpr int   TOT   = B_ * CELLS;         // 2,097,152
constexpr float VS0   = 0.1f, VS1 = 0.1f;
constexpr float PC0   = -51.2f, PC1 = -51.2f;
constexpr float EPS_  = 1e-5f;

constexpr int   PBLK  = (N_ + 255) / 256;   // 977 pass1 blocks per batch
constexpr int   GRID  = 1024;               // fat kernel blocks (4096 waves)
constexpr int   NSTRIPE = (B_ * C_ * CELLS) / 2048;  // 65536 stripes of 2048 cells (8 KB)
constexpr int   NSUB  = 4;                  // sub-chains per cell (round-14)

// ---- d_ws layout (4B units) ----
constexpr int WS_W1T  = 0;                    // [64][10] folded
constexpr int WS_B1   = 640;                  // [64]
constexpr int WS_W2T  = 704;                  // [64][64] c-major
constexpr int WS_B2   = 4800;                 // [64]
constexpr int WS_PZ   = 4864;                 // [B][1024] z partials
constexpr int WS_PM   = WS_PZ + 2048;         // [B][1024] count partials
constexpr int WS_CNT  = WS_PM + 2048;         // occupied-cell counter
constexpr int WS_HEAD = 16384;                // [TOT*NSUB] sub-chain heads (-1 empty)
constexpr int WS_NEXT = WS_HEAD + TOT * NSUB; // [B*N] next-point link (within sub-chain)
constexpr int WS_LIST = WS_NEXT + B_ * N_;    // [<=B*N] occupied cell list
constexpr int WS_BMP  = WS_LIST + B_ * N_;    // [TOT/32] occupancy bitmap
constexpr int WS_END  = WS_BMP + TOT / 32;
constexpr size_t NEED_BYTES = (size_t)WS_END * 4;
}

// Kernel 1: init heads/-1 (4 sub-chains/cell), bitmap/partials/counters/0;
// block 0 folds BN weights.
__global__ __launch_bounds__(256) void init_prep(const float* __restrict__ W1, const float* __restrict__ g1,
                                                 const float* __restrict__ b1, const float* __restrict__ m1,
                                                 const float* __restrict__ v1, const float* __restrict__ W2,
                                                 const float* __restrict__ g2, const float* __restrict__ b2,
                                                 const float* __restrict__ m2, const float* __restrict__ v2,
                                                 float* __restrict__ wsf, int* __restrict__ wsi) {
    const int tid    = blockIdx.x * 256 + threadIdx.x;
    const int stride = gridDim.x * 256;
    i32x4* head4 = (i32x4*)(wsi + WS_HEAD);
    i32x4* bmp4  = (i32x4*)(wsi + WS_BMP);
    const i32x4 mone = {-1, -1, -1, -1};
    const i32x4 zero = {0, 0, 0, 0};
    for (int i = tid; i < TOT * NSUB / 4; i += stride) __builtin_nontemporal_store(mone, head4 + i);
    for (int i = tid; i < TOT / 32 / 4; i += stride) __builtin_nontemporal_store(zero, bmp4 + i);
    if (tid < 1024) ((i32x4*)(wsi + WS_PZ))[tid] = zero;   // PZ+PM (4096 ints)
    if (tid == 0) wsi[WS_CNT] = 0;
    if (blockIdx.x == 0 && threadIdx.x < C_) {
        const int c = threadIdx.x;
        float s1 = g1[c] / sqrtf(v1[c] + EPS_);
        for (int f = 0; f < 10; ++f) wsf[WS_W1T + c * 10 + f] = W1[f * C_ + c] * s1;
        wsf[WS_B1 + c] = b1[c] - m1[c] * s1;
        float s2 = g2[c] / sqrtf(v2[c] + EPS_);
        for (int k = 0; k < C_; ++k) wsf[WS_W2T + c * C_ + k] = W2[k * C_ + c] * s2;
        wsf[WS_B2 + c] = b2[c] - m2[c] * s2;
    }
}

__device__ __forceinline__ int cell_of(float x, float y) {
    int px = (int)floorf((x - PC0) / VS0);
    int py = (int)floorf((y - PC1) / VS1);
    px = px < 0 ? 0 : (px > NX_ - 1 ? NX_ - 1 : px);
    py = py < 0 ? 0 : (py > NY_ - 1 ? NY_ - 1 : py);
    return py * NX_ + px;
}

// Kernel 2: one coalesced sweep — z-mean partials + 4-way sub-chain insert +
// exact occupied-list append via atomicOr's returned old bitmap word.
__global__ __launch_bounds__(256) void pass1(const float* __restrict__ pts,
                                             const int* __restrict__ mask,
                                             float* __restrict__ wsf, int* __restrict__ wsi) {
    const int b = blockIdx.y, t = threadIdx.x;
    const int n = blockIdx.x * 256 + t;
    float sz = 0.f, sm = 0.f;
    if (n < N_ && mask[b * N_ + n]) {
        const size_t pb = ((size_t)b * N_ + n) * 5;
        const float x = pts[pb], y = pts[pb + 1], z = pts[pb + 2];
        const int idx = b * CELLS + cell_of(x, y);
        const int j   = n & (NSUB - 1);
        const int old = atomicExch(&wsi[WS_HEAD + idx * NSUB + j], n);
        wsi[WS_NEXT + b * N_ + n] = old;
        const int bit = 1 << (idx & 31);
        const int ob  = atomicOr(&wsi[WS_BMP + (idx >> 5)], bit);
        if (!(ob & bit)) {   // exactly one thread per cell sees the bit clear
            const int li = atomicAdd(&wsi[WS_CNT], 1);
            wsi[WS_LIST + li] = idx;
        }
        sz = z; sm = 1.f;
    }
    __shared__ float lz[256], lm[256];
    lz[t] = sz; lm[t] = sm;
    __syncthreads();
    for (int s = 128; s > 0; s >>= 1) {
        if (t < s) { lz[t] += lz[t + s]; lm[t] += lm[t + s]; }
        __syncthreads();
    }
    if (t == 0) { wsf[WS_PZ + b * 1024 + blockIdx.x] = lz[0]; wsf[WS_PM + b * 1024 + blockIdx.x] = lm[0]; }
}

// Kernel 3: round-11 structure (compute-then-zero, NO stagger — round-13 A/B
// showed stagger costs +12us from write-flood/chain-load interference).
// Round-14 change: each cell's points split across 4 sub-chains, walked
// interleaved -> 4 independent latency streams per wave while sharing ALL
// cell state (vs round-12's dual-cell ILP which doubled register state).
// fmax is exactly commutative/associative -> bit-identical output.
__global__ __launch_bounds__(256) void fat(const float* __restrict__ pts,
                                           const float* __restrict__ wsf,
                                           const int* __restrict__ wsi,
                                           float* __restrict__ out) {
    __shared__ float red[16];
    const int t    = threadIdx.x;
    const int wid  = t >> 6;
    const int lane = t & 63;
    const int c    = lane;

    // ---- zmean finish: reduce 1024 partials per batch, redundantly per block ----
    float sz0 = 0.f, sm0 = 0.f, sz1 = 0.f, sm1 = 0.f;
#pragma unroll
    for (int k = 0; k < 4; ++k) {
        const int i = t + k * 256;
        sz0 += wsf[WS_PZ + i];        sm0 += wsf[WS_PM + i];
        sz1 += wsf[WS_PZ + 1024 + i]; sm1 += wsf[WS_PM + 1024 + i];
    }
#pragma unroll
    for (int m = 32; m >= 1; m >>= 1) {
        sz0 += __shfl_xor(sz0, m, 64); sm0 += __shfl_xor(sm0, m, 64);
        sz1 += __shfl_xor(sz1, m, 64); sm1 += __shfl_xor(sm1, m, 64);
    }
    if (lane == 0) {
        red[wid * 4 + 0] = sz0; red[wid * 4 + 1] = sm0;
        red[wid * 4 + 2] = sz1; red[wid * 4 + 3] = sm1;
    }
    __syncthreads();
    const float zm0 = (red[0] + red[4] + red[8] + red[12]) /
                      fmaxf(red[1] + red[5] + red[9] + red[13], 1.f);
    const float zm1 = (red[2] + red[6] + red[10] + red[14]) /
                      fmaxf(red[3] + red[7] + red[11] + red[15], 1.f);

    // ---- per-lane folded weights ----
    float w1c[10];
#pragma unroll
    for (int f = 0; f < 10; ++f) w1c[f] = wsf[WS_W1T + c * 10 + f];
    const float b1c = wsf[WS_B1 + c];
    float w2c[C_];
#pragma unroll
    for (int k = 0; k < C_; ++k) w2c[k] = wsf[WS_W2T + c * C_ + k];
    const float b2c = wsf[WS_B2 + c];

    const int W  = blockIdx.x * 4 + wid;
    const int NW = GRID * 4;

    // ---- compute role: occupied cells, 4 interleaved sub-chains per cell ----
    {
        const int cnt = wsi[WS_CNT];
        for (int e = W; e < cnt; e += NW) {
            const int idx  = wsi[WS_LIST + e];
            const int b    = idx >> 20;
            const int cell = idx & (CELLS - 1);
            const float pxf = (float)(cell & (NX_ - 1));
            const float pyf = (float)(cell >> 10);
            const float zmean = b ? zm1 : zm0;
            const int nbase = b * N_;
            float hmax = 0.f;
            int n0 = wsi[WS_HEAD + idx * NSUB + 0];
            int n1 = wsi[WS_HEAD + idx * NSUB + 1];
            int n2 = wsi[WS_HEAD + idx * NSUB + 2];
            int n3 = wsi[WS_HEAD + idx * NSUB + 3];

            auto visit = [&](int n) {
                const size_t pb = ((size_t)nbase + n) * 5;
                const float x = pts[pb], y = pts[pb + 1], z = pts[pb + 2];
                const float it = pts[pb + 3], rg = pts[pb + 4];
                float a = b1c;
                a = fmaf(x,  w1c[0], a);
                a = fmaf(y,  w1c[1], a);
                a = fmaf(z,  w1c[2], a);
                a = fmaf(it, w1c[3], a);
                a = fmaf(rg, w1c[4], a);
                a = fmaf(x - (pxf * VS0 + PC0 + VS0 * 0.5f), w1c[5], a);
                a = fmaf(y - (pyf * VS1 + PC1 + VS1 * 0.5f), w1c[6], a);
                a = fmaf(z - zmean,                          w1c[7], a);
                a = fmaf(x - (pxf * VS0 + PC0),              w1c[8], a);
                a = fmaf(y - (pyf * VS1 + PC1),              w1c[9], a);
                const int h1i = __float_as_int(fmaxf(a, 0.f));   // lane k holds h1[k]
                float ac0 = 0.f, ac1 = 0.f, ac2 = 0.f, ac3 = 0.f;
#pragma unroll
                for (int k = 0; k < 16; ++k) {   // same k-order + 4-way split as rounds 2-13
                    ac0 = fmaf(__int_as_float(__builtin_amdgcn_readlane(h1i, 4 * k + 0)), w2c[4 * k + 0], ac0);
                    ac1 = fmaf(__int_as_float(__builtin_amdgcn_readlane(h1i, 4 * k + 1)), w2c[4 * k + 1], ac1);
                    ac2 = fmaf(__int_as_float(__builtin_amdgcn_readlane(h1i, 4 * k + 2)), w2c[4 * k + 2], ac2);
                    ac3 = fmaf(__int_as_float(__builtin_amdgcn_readlane(h1i, 4 * k + 3)), w2c[4 * k + 3], ac3);
                }
                hmax = fmaxf(hmax, b2c + ((ac0 + ac1) + (ac2 + ac3)));
            };

            while ((n0 != -1) | (n1 != -1) | (n2 != -1) | (n3 != -1)) {
                int nx0 = -1, nx1 = -1, nx2 = -1, nx3 = -1;
                if (n0 != -1) nx0 = wsi[WS_NEXT + nbase + n0];   // 4 independent
                if (n1 != -1) nx1 = wsi[WS_NEXT + nbase + n1];   // latency streams
                if (n2 != -1) nx2 = wsi[WS_NEXT + nbase + n2];
                if (n3 != -1) nx3 = wsi[WS_NEXT + nbase + n3];
                if (n0 != -1) visit(n0);
                if (n1 != -1) visit(n1);
                if (n2 != -1) visit(n2);
                if (n3 != -1) visit(n3);
                n0 = nx0; n1 = nx1; n2 = nx2; n3 = nx3;
            }
            out[(((size_t)b * C_ + c) << 20) + cell] = hmax;
        }
    }

    // ---- zero role: 2048-cell stripes, one bitmap word per lane ----
    {
        f32x4* out4 = (f32x4*)out;
        const f32x4 z4 = {0.f, 0.f, 0.f, 0.f};
        for (int s = W; s < NSTRIPE; s += NW) {
            const int p  = s >> 9;          // plane = b*64 + ch
            const int q  = s & 511;         // stripe within plane (2048 cells)
            const int bb = p >> 6;
            const int Wd = wsi[WS_BMP + bb * (CELLS / 32) + q * 64 + lane];
            const int ib = (p << 18) + (q << 9);   // f32x4 base index of stripe
            if (__ballot(Wd != 0) == 0ULL) {
#pragma unroll
                for (int k = 0; k < 8; ++k)
                    __builtin_nontemporal_store(z4, out4 + (ib + k * 64 + lane));
            } else {
#pragma unroll
                for (int k = 0; k < 8; ++k) {
                    const unsigned w   = (unsigned)__shfl(Wd, k * 8 + (lane >> 3), 64);
                    const unsigned nib = (w >> ((lane & 7) * 4)) & 0xFu;
                    const int i = ib + k * 64 + lane;
                    if (nib == 0u) {
                        __builtin_nontemporal_store(z4, out4 + i);
                    } else {
#pragma unroll
                        for (int jj = 0; jj < 4; ++jj)
                            if (!((nib >> jj) & 1u)) out[(size_t)i * 4 + jj] = 0.f;
                    }
                }
            }
        }
    }
}

// ---------------- fallback path (round-2, atomic scatter) ----------------
__global__ void prep_weights_fb(const float* __restrict__ W1, const float* __restrict__ g1,
                                const float* __restrict__ b1, const float* __restrict__ m1,
                                const float* __restrict__ v1, const float* __restrict__ W2,
                                const float* __restrict__ g2, const float* __restrict__ b2,
                                const float* __restrict__ m2, const float* __restrict__ v2,
                                float* __restrict__ ws) {
    int c = threadIdx.x;
    if (c >= C_) return;
    float s1 = g1[c] / sqrtf(v1[c] + EPS_);
    for (int f = 0; f < 10; ++f) ws[WS_W1T + c * 10 + f] = W1[f * C_ + c] * s1;
    ws[WS_B1 + c] = b1[c] - m1[c] * s1;
    float s2 = g2[c] / sqrtf(v2[c] + EPS_);
    for (int k = 0; k < C_; ++k) ws[WS_W2T + c * C_ + k] = W2[k * C_ + c] * s2;
    ws[WS_B2 + c] = b2[c] - m2[c] * s2;
}

__global__ void zmean_fb1(const float* __restrict__ pts, const int* __restrict__ mask,
                          float* __restrict__ ws) {
    const int b = blockIdx.y, t = threadIdx.x;
    const int n = blockIdx.x * 256 + t;
    float sz = 0.f, sm = 0.f;
    if (n < N_ && mask[b * N_ + n]) {
        sz = pts[((size_t)b * N_ + n) * 5 + 2];
        sm = 1.f;
    }
    __shared__ float lz[256], lm[256];
    lz[t] = sz; lm[t] = sm;
    __syncthreads();
    for (int s = 128; s > 0; s >>= 1) {
        if (t < s) { lz[t] += lz[t + s]; lm[t] += lm[t + s]; }
        __syncthreads();
    }
    if (t == 0) { ws[WS_PZ + b * 1024 + blockIdx.x] = lz[0]; ws[WS_PM + b * 1024 + blockIdx.x] = lm[0]; }
}

__global__ void zmean_fb2(float* __restrict__ ws) {
    const int b = blockIdx.x, t = threadIdx.x;
    __shared__ float lz[256], lm[256];
    float sz = 0.f, sm = 0.f;
    for (int k = t; k < 1024; k += 256) {
        sz += (k < PBLK) ? ws[WS_PZ + b * 1024 + k] : 0.f;
        sm += (k < PBLK) ? ws[WS_PM + b * 1024 + k] : 0.f;
    }
    lz[t] = sz; lm[t] = sm;
    __syncthreads();
    for (int s = 128; s > 0; s >>= 1) {
        if (t < s) { lz[t] += lz[t + s]; lm[t] += lm[t + s]; }
        __syncthreads();
    }
    if (t == 0) ws[WS_CNT + 2 + b] = lz[0] / fmaxf(lm[0], 1.f);  // stash zmean
}

__global__ __launch_bounds__(256) void pfn_scatter_fb(const float* __restrict__ pts,
                                                      const int* __restrict__ mask,
                                                      const float* __restrict__ ws,
                                                      float* __restrict__ out) {
    const int b = blockIdx.y;
    const int n = blockIdx.x * 256 + threadIdx.x;
    if (n >= N_) return;
    if (!mask[b * N_ + n]) return;
    const float zmean = ws[WS_CNT + 2 + b];
    const size_t pbase = ((size_t)b * N_ + n) * 5;
    const float x = pts[pbase], y = pts[pbase + 1], z = pts[pbase + 2];
    const float it = pts[pbase + 3], rg = pts[pbase + 4];
    const int cell = cell_of(x, y);
    const float pxf = (float)(cell & (NX_ - 1)), pyf = (float)(cell >> 10);
    float aug[10];
    aug[0] = x; aug[1] = y; aug[2] = z; aug[3] = it; aug[4] = rg;
    aug[5] = x - (pxf * VS0 + PC0 + VS0 * 0.5f);
    aug[6] = y - (pyf * VS1 + PC1 + VS1 * 0.5f);
    aug[7] = z - zmean;
    aug[8] = x - (pxf * VS0 + PC0);
    aug[9] = y - (pyf * VS1 + PC1);
    float h1[C_];
#pragma unroll
    for (int c = 0; c < C_; ++c) {
        float acc = ws[WS_B1 + c];
#pragma unroll
        for (int f = 0; f < 10; ++f) acc = fmaf(aug[f], ws[WS_W1T + c * 10 + f], acc);
        h1[c] = fmaxf(acc, 0.f);
    }
    unsigned int* ob = (unsigned int*)out + (size_t)b * C_ * CELLS + cell;
#pragma unroll 4
    for (int c = 0; c < C_; ++c) {
        float acc = ws[WS_B2 + c];
#pragma unroll
        for (int k = 0; k < C_; ++k) acc = fmaf(h1[k], ws[WS_W2T + c * C_ + k], acc);
        if (acc > 0.f) atomicMax(ob + (size_t)c * CELLS, __float_as_uint(acc));
    }
}

extern "C" void kernel_launch(void* const* d_in, const int* in_sizes, int n_in,
                              void* d_out, int out_size, void* d_ws, size_t ws_size,
                              hipStream_t stream) {
    const float* pts  = (const float*)d_in[0];
    const int*   mask = (const int*)d_in[1];
    const float* W1 = (const float*)d_in[2];
    const float* g1 = (const float*)d_in[3];
    const float* b1 = (const float*)d_in[4];
    const float* m1 = (const float*)d_in[5];
    const float* v1 = (const float*)d_in[6];
    const float* W2 = (const float*)d_in[7];
    const float* g2 = (const float*)d_in[8];
    const float* b2 = (const float*)d_in[9];
    const float* m2 = (const float*)d_in[10];
    const float* v2 = (const float*)d_in[11];
    float* wsf = (float*)d_ws;
    int*   wsi = (int*)d_ws;
    float* out = (float*)d_out;

    if (ws_size >= NEED_BYTES) {
        init_prep<<<512, 256, 0, stream>>>(W1, g1, b1, m1, v1, W2, g2, b2, m2, v2, wsf, wsi);
        pass1<<<dim3(PBLK, B_), 256, 0, stream>>>(pts, mask, wsf, wsi);
        fat<<<GRID, 256, 0, stream>>>(pts, wsf, wsi, out);
    } else {
        hipMemsetAsync(d_out, 0, (size_t)out_size * sizeof(float), stream);
        hipMemsetAsync((char*)d_ws + (size_t)WS_PZ * 4, 0, 4096 * 4, stream);
        prep_weights_fb<<<1, 256, 0, stream>>>(W1, g1, b1, m1, v1, W2, g2, b2, m2, v2, wsf);
        zmean_fb1<<<dim3(PBLK, B_), 256, 0, stream>>>(pts, mask, wsf);
        zmean_fb2<<<B_, 256, 0, stream>>>(wsf);
        pfn_scatter_fb<<<dim3((N_ + 255) / 256, B_), 256, 0, stream>>>(pts, mask, wsf, out);
    }
}

// Round 15
// 223.062 us; speedup vs baseline: 1.1781x; 1.1781x over previous
//
#include <hip/hip_runtime.h>

typedef float f32x4 __attribute__((ext_vector_type(4)));
typedef int   i32x4 __attribute__((ext_vector_type(4)));

namespace {
constexpr int   B_    = 2;
constexpr int   N_    = 250000;
constexpr int   C_    = 64;
constexpr int   NX_   = 1024;
constexpr int   NY_   = 1024;
constexpr int   CELLS = NX_ * NY_;          // 1<<20
constexpr int   TOT   = B_ * CELLS;         // 2,097,152
constexpr float VS0   = 0.1f, VS1 = 0.1f;
constexpr float PC0   = -51.2f, PC1 = -51.2f;
constexpr float EPS_  = 1e-5f;

constexpr int   PBLK  = (N_ + 255) / 256;   // 977 pass1 blocks per batch
// Round-15: GRID 1024->2048. fat's VGPR=80 allows 6 waves/SIMD but GRID=1024
// launched only 4/SIMD (16 waves/CU) — grid was the occupancy cap, not regs.
constexpr int   GRID  = 2048;               // fat kernel blocks (8192 waves)
constexpr int   NSTRIPE = (B_ * C_ * CELLS) / 2048;  // 65536 stripes of 2048 cells (8 KB)

// ---- d_ws layout (4B units) ----
constexpr int WS_W1T  = 0;                    // [64][10] folded
constexpr int WS_B1   = 640;                  // [64]
constexpr int WS_W2T  = 704;                  // [64][64] c-major
constexpr int WS_B2   = 4800;                 // [64]
constexpr int WS_PZ   = 4864;                 // [B][1024] z partials
constexpr int WS_PM   = WS_PZ + 2048;         // [B][1024] count partials
constexpr int WS_CNT  = WS_PM + 2048;         // occupied-cell counter
constexpr int WS_HEAD = 16384;                // [TOT] per-cell list head (-1 empty)
constexpr int WS_NEXT = WS_HEAD + TOT;        // [B*N] next-point link
constexpr int WS_LIST = WS_NEXT + B_ * N_;    // [<=B*N] occupied cell list
constexpr int WS_BMP  = WS_LIST + B_ * N_;    // [TOT/32] occupancy bitmap
constexpr int WS_END  = WS_BMP + TOT / 32;
constexpr size_t NEED_BYTES = (size_t)WS_END * 4;
}

// Kernel 1: init head/-1, bitmap/partials/counters/0; block 0 folds BN weights.
__global__ __launch_bounds__(256) void init_prep(const float* __restrict__ W1, const float* __restrict__ g1,
                                                 const float* __restrict__ b1, const float* __restrict__ m1,
                                                 const float* __restrict__ v1, const float* __restrict__ W2,
                                                 const float* __restrict__ g2, const float* __restrict__ b2,
                                                 const float* __restrict__ m2, const float* __restrict__ v2,
                                                 float* __restrict__ wsf, int* __restrict__ wsi) {
    const int tid    = blockIdx.x * 256 + threadIdx.x;
    const int stride = gridDim.x * 256;
    i32x4* head4 = (i32x4*)(wsi + WS_HEAD);
    i32x4* bmp4  = (i32x4*)(wsi + WS_BMP);
    const i32x4 mone = {-1, -1, -1, -1};
    const i32x4 zero = {0, 0, 0, 0};
    for (int i = tid; i < TOT / 4; i += stride) __builtin_nontemporal_store(mone, head4 + i);
    for (int i = tid; i < TOT / 32 / 4; i += stride) __builtin_nontemporal_store(zero, bmp4 + i);
    if (tid < 1024) ((i32x4*)(wsi + WS_PZ))[tid] = zero;   // PZ+PM (4096 ints)
    if (tid == 0) wsi[WS_CNT] = 0;
    if (blockIdx.x == 0 && threadIdx.x < C_) {
        const int c = threadIdx.x;
        float s1 = g1[c] / sqrtf(v1[c] + EPS_);
        for (int f = 0; f < 10; ++f) wsf[WS_W1T + c * 10 + f] = W1[f * C_ + c] * s1;
        wsf[WS_B1 + c] = b1[c] - m1[c] * s1;
        float s2 = g2[c] / sqrtf(v2[c] + EPS_);
        for (int k = 0; k < C_; ++k) wsf[WS_W2T + c * C_ + k] = W2[k * C_ + c] * s2;
        wsf[WS_B2 + c] = b2[c] - m2[c] * s2;
    }
}

__device__ __forceinline__ int cell_of(float x, float y) {
    int px = (int)floorf((x - PC0) / VS0);
    int py = (int)floorf((y - PC1) / VS1);
    px = px < 0 ? 0 : (px > NX_ - 1 ? NX_ - 1 : px);
    py = py < 0 ? 0 : (py > NY_ - 1 ? NY_ - 1 : py);
    return py * NX_ + px;
}

// Kernel 2: one coalesced sweep — z-mean partials + linked-list insert +
// occupied-list append + bitmap set (first insert per cell).
__global__ __launch_bounds__(256) void pass1(const float* __restrict__ pts,
                                             const int* __restrict__ mask,
                                             float* __restrict__ wsf, int* __restrict__ wsi) {
    const int b = blockIdx.y, t = threadIdx.x;
    const int n = blockIdx.x * 256 + t;
    float sz = 0.f, sm = 0.f;
    if (n < N_ && mask[b * N_ + n]) {
        const size_t pb = ((size_t)b * N_ + n) * 5;
        const float x = pts[pb], y = pts[pb + 1], z = pts[pb + 2];
        const int idx = b * CELLS + cell_of(x, y);
        const int old = atomicExch(&wsi[WS_HEAD + idx], n);
        wsi[WS_NEXT + b * N_ + n] = old;
        if (old == -1) {
            const int li = atomicAdd(&wsi[WS_CNT], 1);
            wsi[WS_LIST + li] = idx;
            atomicOr(&wsi[WS_BMP + (idx >> 5)], 1 << (idx & 31));
        }
        sz = z; sm = 1.f;
    }
    __shared__ float lz[256], lm[256];
    lz[t] = sz; lm[t] = sm;
    __syncthreads();
    for (int s = 128; s > 0; s >>= 1) {
        if (t < s) { lz[t] += lz[t + s]; lm[t] += lm[t + s]; }
        __syncthreads();
    }
    if (t == 0) { wsf[WS_PZ + b * 1024 + blockIdx.x] = lz[0]; wsf[WS_PM + b * 1024 + blockIdx.x] = lm[0]; }
}

// Kernel 3: round-11 body VERBATIM (single-chain walk, readlane GEMV2,
// compute-then-zero, no stagger). Only GRID changed 1024->2048 so resident
// occupancy is VGPR-limited (6 waves/SIMD at VGPR=80) instead of grid-limited
// (4 waves/SIMD) — tests the latency/TLP hypothesis with one variable.
__global__ __launch_bounds__(256) void fat(const float* __restrict__ pts,
                                           const float* __restrict__ wsf,
                                           const int* __restrict__ wsi,
                                           float* __restrict__ out) {
    __shared__ float red[16];
    const int t    = threadIdx.x;
    const int wid  = t >> 6;
    const int lane = t & 63;
    const int c    = lane;

    // ---- zmean finish: reduce 1024 partials per batch, redundantly per block ----
    float sz0 = 0.f, sm0 = 0.f, sz1 = 0.f, sm1 = 0.f;
#pragma unroll
    for (int k = 0; k < 4; ++k) {
        const int i = t + k * 256;
        sz0 += wsf[WS_PZ + i];        sm0 += wsf[WS_PM + i];
        sz1 += wsf[WS_PZ + 1024 + i]; sm1 += wsf[WS_PM + 1024 + i];
    }
#pragma unroll
    for (int m = 32; m >= 1; m >>= 1) {
        sz0 += __shfl_xor(sz0, m, 64); sm0 += __shfl_xor(sm0, m, 64);
        sz1 += __shfl_xor(sz1, m, 64); sm1 += __shfl_xor(sm1, m, 64);
    }
    if (lane == 0) {
        red[wid * 4 + 0] = sz0; red[wid * 4 + 1] = sm0;
        red[wid * 4 + 2] = sz1; red[wid * 4 + 3] = sm1;
    }
    __syncthreads();
    const float zm0 = (red[0] + red[4] + red[8] + red[12]) /
                      fmaxf(red[1] + red[5] + red[9] + red[13], 1.f);
    const float zm1 = (red[2] + red[6] + red[10] + red[14]) /
                      fmaxf(red[3] + red[7] + red[11] + red[15], 1.f);

    // ---- per-lane folded weights ----
    float w1c[10];
#pragma unroll
    for (int f = 0; f < 10; ++f) w1c[f] = wsf[WS_W1T + c * 10 + f];
    const float b1c = wsf[WS_B1 + c];
    float w2c[C_];
#pragma unroll
    for (int k = 0; k < C_; ++k) w2c[k] = wsf[WS_W2T + c * C_ + k];
    const float b2c = wsf[WS_B2 + c];

    const int W  = blockIdx.x * 4 + wid;
    const int NW = GRID * 4;

    // ---- compute role: occupied cells, strided over all waves ----
    {
        const int cnt = wsi[WS_CNT];
        for (int e = W; e < cnt; e += NW) {
            const int idx  = wsi[WS_LIST + e];
            const int b    = idx >> 20;
            const int cell = idx & (CELLS - 1);
            const float pxf = (float)(cell & (NX_ - 1));
            const float pyf = (float)(cell >> 10);
            const float zmean = b ? zm1 : zm0;
            float hmax = 0.f;
            int n = wsi[WS_HEAD + idx];
            while (n != -1) {
                const int nx = wsi[WS_NEXT + b * N_ + n];   // issue chain load early
                const size_t pb = ((size_t)b * N_ + n) * 5;
                const float x = pts[pb], y = pts[pb + 1], z = pts[pb + 2];
                const float it = pts[pb + 3], rg = pts[pb + 4];
                float a = b1c;
                a = fmaf(x,  w1c[0], a);
                a = fmaf(y,  w1c[1], a);
                a = fmaf(z,  w1c[2], a);
                a = fmaf(it, w1c[3], a);
                a = fmaf(rg, w1c[4], a);
                a = fmaf(x - (pxf * VS0 + PC0 + VS0 * 0.5f), w1c[5], a);
                a = fmaf(y - (pyf * VS1 + PC1 + VS1 * 0.5f), w1c[6], a);
                a = fmaf(z - zmean,                          w1c[7], a);
                a = fmaf(x - (pxf * VS0 + PC0),              w1c[8], a);
                a = fmaf(y - (pyf * VS1 + PC1),              w1c[9], a);
                const int h1i = __float_as_int(fmaxf(a, 0.f));   // lane k holds h1[k]
                float ac0 = 0.f, ac1 = 0.f, ac2 = 0.f, ac3 = 0.f;
#pragma unroll
                for (int k = 0; k < 16; ++k) {   // same k-order + 4-way split as rounds 2-14
                    ac0 = fmaf(__int_as_float(__builtin_amdgcn_readlane(h1i, 4 * k + 0)), w2c[4 * k + 0], ac0);
                    ac1 = fmaf(__int_as_float(__builtin_amdgcn_readlane(h1i, 4 * k + 1)), w2c[4 * k + 1], ac1);
                    ac2 = fmaf(__int_as_float(__builtin_amdgcn_readlane(h1i, 4 * k + 2)), w2c[4 * k + 2], ac2);
                    ac3 = fmaf(__int_as_float(__builtin_amdgcn_readlane(h1i, 4 * k + 3)), w2c[4 * k + 3], ac3);
                }
                hmax = fmaxf(hmax, b2c + ((ac0 + ac1) + (ac2 + ac3)));
                n = nx;
            }
            out[(((size_t)b * C_ + c) << 20) + cell] = hmax;
        }
    }

    // ---- zero role: 2048-cell stripes, one bitmap word per lane ----
    {
        f32x4* out4 = (f32x4*)out;
        const f32x4 z4 = {0.f, 0.f, 0.f, 0.f};
        for (int s = W; s < NSTRIPE; s += NW) {
            const int p  = s >> 9;          // plane = b*64 + ch
            const int q  = s & 511;         // stripe within plane (2048 cells)
            const int bb = p >> 6;
            const int Wd = wsi[WS_BMP + bb * (CELLS / 32) + q * 64 + lane];
            const int ib = (p << 18) + (q << 9);   // f32x4 base index of stripe
            if (__ballot(Wd != 0) == 0ULL) {
#pragma unroll
                for (int k = 0; k < 8; ++k)
                    __builtin_nontemporal_store(z4, out4 + (ib + k * 64 + lane));
            } else {
#pragma unroll
                for (int k = 0; k < 8; ++k) {
                    const unsigned w   = (unsigned)__shfl(Wd, k * 8 + (lane >> 3), 64);
                    const unsigned nib = (w >> ((lane & 7) * 4)) & 0xFu;
                    const int i = ib + k * 64 + lane;
                    if (nib == 0u) {
                        __builtin_nontemporal_store(z4, out4 + i);
                    } else {
#pragma unroll
                        for (int jj = 0; jj < 4; ++jj)
                            if (!((nib >> jj) & 1u)) out[(size_t)i * 4 + jj] = 0.f;
                    }
                }
            }
        }
    }
}

// ---------------- fallback path (round-2, atomic scatter) ----------------
__global__ void prep_weights_fb(const float* __restrict__ W1, const float* __restrict__ g1,
                                const float* __restrict__ b1, const float* __restrict__ m1,
                                const float* __restrict__ v1, const float* __restrict__ W2,
                                const float* __restrict__ g2, const float* __restrict__ b2,
                                const float* __restrict__ m2, const float* __restrict__ v2,
                                float* __restrict__ ws) {
    int c = threadIdx.x;
    if (c >= C_) return;
    float s1 = g1[c] / sqrtf(v1[c] + EPS_);
    for (int f = 0; f < 10; ++f) ws[WS_W1T + c * 10 + f] = W1[f * C_ + c] * s1;
    ws[WS_B1 + c] = b1[c] - m1[c] * s1;
    float s2 = g2[c] / sqrtf(v2[c] + EPS_);
    for (int k = 0; k < C_; ++k) ws[WS_W2T + c * C_ + k] = W2[k * C_ + c] * s2;
    ws[WS_B2 + c] = b2[c] - m2[c] * s2;
}

__global__ void zmean_fb1(const float* __restrict__ pts, const int* __restrict__ mask,
                          float* __restrict__ ws) {
    const int b = blockIdx.y, t = threadIdx.x;
    const int n = blockIdx.x * 256 + t;
    float sz = 0.f, sm = 0.f;
    if (n < N_ && mask[b * N_ + n]) {
        sz = pts[((size_t)b * N_ + n) * 5 + 2];
        sm = 1.f;
    }
    __shared__ float lz[256], lm[256];
    lz[t] = sz; lm[t] = sm;
    __syncthreads();
    for (int s = 128; s > 0; s >>= 1) {
        if (t < s) { lz[t] += lz[t + s]; lm[t] += lm[t + s]; }
        __syncthreads();
    }
    if (t == 0) { ws[WS_PZ + b * 1024 + blockIdx.x] = lz[0]; ws[WS_PM + b * 1024 + blockIdx.x] = lm[0]; }
}

__global__ void zmean_fb2(float* __restrict__ ws) {
    const int b = blockIdx.x, t = threadIdx.x;
    __shared__ float lz[256], lm[256];
    float sz = 0.f, sm = 0.f;
    for (int k = t; k < 1024; k += 256) {
        sz += (k < PBLK) ? ws[WS_PZ + b * 1024 + k] : 0.f;
        sm += (k < PBLK) ? ws[WS_PM + b * 1024 + k] : 0.f;
    }
    lz[t] = sz; lm[t] = sm;
    __syncthreads();
    for (int s = 128; s > 0; s >>= 1) {
        if (t < s) { lz[t] += lz[t + s]; lm[t] += lm[t + s]; }
        __syncthreads();
    }
    if (t == 0) ws[WS_CNT + 2 + b] = lz[0] / fmaxf(lm[0], 1.f);  // stash zmean
}

__global__ __launch_bounds__(256) void pfn_scatter_fb(const float* __restrict__ pts,
                                                      const int* __restrict__ mask,
                                                      const float* __restrict__ ws,
                                                      float* __restrict__ out) {
    const int b = blockIdx.y;
    const int n = blockIdx.x * 256 + threadIdx.x;
    if (n >= N_) return;
    if (!mask[b * N_ + n]) return;
    const float zmean = ws[WS_CNT + 2 + b];
    const size_t pbase = ((size_t)b * N_ + n) * 5;
    const float x = pts[pbase], y = pts[pbase + 1], z = pts[pbase + 2];
    const float it = pts[pbase + 3], rg = pts[pbase + 4];
    const int cell = cell_of(x, y);
    const float pxf = (float)(cell & (NX_ - 1)), pyf = (float)(cell >> 10);
    float aug[10];
    aug[0] = x; aug[1] = y; aug[2] = z; aug[3] = it; aug[4] = rg;
    aug[5] = x - (pxf * VS0 + PC0 + VS0 * 0.5f);
    aug[6] = y - (pyf * VS1 + PC1 + VS1 * 0.5f);
    aug[7] = z - zmean;
    aug[8] = x - (pxf * VS0 + PC0);
    aug[9] = y - (pyf * VS1 + PC1);
    float h1[C_];
#pragma unroll
    for (int c = 0; c < C_; ++c) {
        float acc = ws[WS_B1 + c];
#pragma unroll
        for (int f = 0; f < 10; ++f) acc = fmaf(aug[f], ws[WS_W1T + c * 10 + f], acc);
        h1[c] = fmaxf(acc, 0.f);
    }
    unsigned int* ob = (unsigned int*)out + (size_t)b * C_ * CELLS + cell;
#pragma unroll 4
    for (int c = 0; c < C_; ++c) {
        float acc = ws[WS_B2 + c];
#pragma unroll
        for (int k = 0; k < C_; ++k) acc = fmaf(h1[k], ws[WS_W2T + c * C_ + k], acc);
        if (acc > 0.f) atomicMax(ob + (size_t)c * CELLS, __float_as_uint(acc));
    }
}

extern "C" void kernel_launch(void* const* d_in, const int* in_sizes, int n_in,
                              void* d_out, int out_size, void* d_ws, size_t ws_size,
                              hipStream_t stream) {
    const float* pts  = (const float*)d_in[0];
    const int*   mask = (const int*)d_in[1];
    const float* W1 = (const float*)d_in[2];
    const float* g1 = (const float*)d_in[3];
    const float* b1 = (const float*)d_in[4];
    const float* m1 = (const float*)d_in[5];
    const float* v1 = (const float*)d_in[6];
    const float* W2 = (const float*)d_in[7];
    const float* g2 = (const float*)d_in[8];
    const float* b2 = (const float*)d_in[9];
    const float* m2 = (const float*)d_in[10];
    const float* v2 = (const float*)d_in[11];
    float* wsf = (float*)d_ws;
    int*   wsi = (int*)d_ws;
    float* out = (float*)d_out;

    if (ws_size >= NEED_BYTES) {
        init_prep<<<512, 256, 0, stream>>>(W1, g1, b1, m1, v1, W2, g2, b2, m2, v2, wsf, wsi);
        pass1<<<dim3(PBLK, B_), 256, 0, stream>>>(pts, mask, wsf, wsi);
        fat<<<GRID, 256, 0, stream>>>(pts, wsf, wsi, out);
    } else {
        hipMemsetAsync(d_out, 0, (size_t)out_size * sizeof(float), stream);
        hipMemsetAsync((char*)d_ws + (size_t)WS_PZ * 4, 0, 4096 * 4, stream);
        prep_weights_fb<<<1, 256, 0, stream>>>(W1, g1, b1, m1, v1, W2, g2, b2, m2, v2, wsf);
        zmean_fb1<<<dim3(PBLK, B_), 256, 0, stream>>>(pts, mask, wsf);
        zmean_fb2<<<B_, 256, 0, stream>>>(wsf);
        pfn_scatter_fb<<<dim3((N_ + 255) / 256, B_), 256, 0, stream>>>(pts, mask, wsf, out);
    }
}

// Round 16
// 214.229 us; speedup vs baseline: 1.2267x; 1.0412x over previous
//
#include <hip/hip_runtime.h>

typedef float f32x4 __attribute__((ext_vector_type(4)));
typedef int   i32x4 __attribute__((ext_vector_type(4)));

namespace {
constexpr int   B_    = 2;
constexpr int   N_    = 250000;
constexpr int   C_    = 64;
constexpr int   NX_   = 1024;
constexpr int   NY_   = 1024;
constexpr int   CELLS = NX_ * NY_;          // 1<<20
constexpr int   TOT   = B_ * CELLS;         // 2,097,152
constexpr float VS0   = 0.1f, VS1 = 0.1f;
constexpr float PC0   = -51.2f, PC1 = -51.2f;
constexpr float EPS_  = 1e-5f;

constexpr int   PBLK  = (N_ + 255) / 256;   // 977 pass1 blocks per batch
constexpr int   GRID  = 2048;               // fat kernel blocks (8192 waves)
constexpr int   NSTRIPE = (B_ * C_ * CELLS) / 2048;  // 65536 stripes of 2048 cells (8 KB)

// ---- d_ws layout (4B units) ----
constexpr int WS_W1T  = 0;                    // [64][10] folded
constexpr int WS_B1   = 640;                  // [64]
constexpr int WS_W2T  = 704;                  // [64][64] c-major
constexpr int WS_B2   = 4800;                 // [64]
constexpr int WS_PZ   = 4864;                 // [B][1024] z partials
constexpr int WS_PM   = WS_PZ + 2048;         // [B][1024] count partials
constexpr int WS_CNT  = WS_PM + 2048;         // occupied-cell counter
constexpr int WS_HEAD = 16384;                // [TOT] per-cell list head (-1 empty)
constexpr int WS_NEXT = WS_HEAD + TOT;        // [B*N] next-point link
constexpr int WS_LIST = WS_NEXT + B_ * N_;    // [<=B*N] occupied cell list
constexpr int WS_BMP  = WS_LIST + B_ * N_;    // [TOT/32] occupancy bitmap
constexpr int WS_END  = WS_BMP + TOT / 32;
constexpr size_t NEED_BYTES = (size_t)WS_END * 4;
}

// Kernel 1: init head/-1, bitmap/partials/counters/0; block 0 folds BN weights.
__global__ __launch_bounds__(256) void init_prep(const float* __restrict__ W1, const float* __restrict__ g1,
                                                 const float* __restrict__ b1, const float* __restrict__ m1,
                                                 const float* __restrict__ v1, const float* __restrict__ W2,
                                                 const float* __restrict__ g2, const float* __restrict__ b2,
                                                 const float* __restrict__ m2, const float* __restrict__ v2,
                                                 float* __restrict__ wsf, int* __restrict__ wsi) {
    const int tid    = blockIdx.x * 256 + threadIdx.x;
    const int stride = gridDim.x * 256;
    i32x4* head4 = (i32x4*)(wsi + WS_HEAD);
    i32x4* bmp4  = (i32x4*)(wsi + WS_BMP);
    const i32x4 mone = {-1, -1, -1, -1};
    const i32x4 zero = {0, 0, 0, 0};
    for (int i = tid; i < TOT / 4; i += stride) __builtin_nontemporal_store(mone, head4 + i);
    for (int i = tid; i < TOT / 32 / 4; i += stride) __builtin_nontemporal_store(zero, bmp4 + i);
    if (tid < 1024) ((i32x4*)(wsi + WS_PZ))[tid] = zero;   // PZ+PM (4096 ints)
    if (tid == 0) wsi[WS_CNT] = 0;
    if (blockIdx.x == 0 && threadIdx.x < C_) {
        const int c = threadIdx.x;
        float s1 = g1[c] / sqrtf(v1[c] + EPS_);
        for (int f = 0; f < 10; ++f) wsf[WS_W1T + c * 10 + f] = W1[f * C_ + c] * s1;
        wsf[WS_B1 + c] = b1[c] - m1[c] * s1;
        float s2 = g2[c] / sqrtf(v2[c] + EPS_);
        for (int k = 0; k < C_; ++k) wsf[WS_W2T + c * C_ + k] = W2[k * C_ + c] * s2;
        wsf[WS_B2 + c] = b2[c] - m2[c] * s2;
    }
}

__device__ __forceinline__ int cell_of(float x, float y) {
    int px = (int)floorf((x - PC0) / VS0);
    int py = (int)floorf((y - PC1) / VS1);
    px = px < 0 ? 0 : (px > NX_ - 1 ? NX_ - 1 : px);
    py = py < 0 ? 0 : (py > NY_ - 1 ? NY_ - 1 : py);
    return py * NX_ + px;
}

// Kernel 2: one coalesced sweep — z-mean partials + linked-list insert +
// occupied-list append + bitmap set (first insert per cell).
__global__ __launch_bounds__(256) void pass1(const float* __restrict__ pts,
                                             const int* __restrict__ mask,
                                             float* __restrict__ wsf, int* __restrict__ wsi) {
    const int b = blockIdx.y, t = threadIdx.x;
    const int n = blockIdx.x * 256 + t;
    float sz = 0.f, sm = 0.f;
    if (n < N_ && mask[b * N_ + n]) {
        const size_t pb = ((size_t)b * N_ + n) * 5;
        const float x = pts[pb], y = pts[pb + 1], z = pts[pb + 2];
        const int idx = b * CELLS + cell_of(x, y);
        const int old = atomicExch(&wsi[WS_HEAD + idx], n);
        wsi[WS_NEXT + b * N_ + n] = old;
        if (old == -1) {
            const int li = atomicAdd(&wsi[WS_CNT], 1);
            wsi[WS_LIST + li] = idx;
            atomicOr(&wsi[WS_BMP + (idx >> 5)], 1 << (idx & 31));
        }
        sz = z; sm = 1.f;
    }
    __shared__ float lz[256], lm[256];
    lz[t] = sz; lm[t] = sm;
    __syncthreads();
    for (int s = 128; s > 0; s >>= 1) {
        if (t < s) { lz[t] += lz[t + s]; lm[t] += lm[t + s]; }
        __syncthreads();
    }
    if (t == 0) { wsf[WS_PZ + b * 1024 + blockIdx.x] = lz[0]; wsf[WS_PM + b * 1024 + blockIdx.x] = lm[0]; }
}

// Kernel 3: round-15 structure; ONLY change: the chain walk is 2-deep
// software-pipelined — each iteration issues NEXT[n1] and pts[n1] (addresses
// ready from last iteration) and computes on point n0's already-loaded data,
// so every load has a full visit (~290cy) of compute between issue and use
// (round-15 analysis: pts[n] was consumed ~20 instr after issue -> ~160cy
// exposed per visit). Visit order unchanged -> bit-identical output.
__global__ __launch_bounds__(256) void fat(const float* __restrict__ pts,
                                           const float* __restrict__ wsf,
                                           const int* __restrict__ wsi,
                                           float* __restrict__ out) {
    __shared__ float red[16];
    const int t    = threadIdx.x;
    const int wid  = t >> 6;
    const int lane = t & 63;
    const int c    = lane;

    // ---- zmean finish: reduce 1024 partials per batch, redundantly per block ----
    float sz0 = 0.f, sm0 = 0.f, sz1 = 0.f, sm1 = 0.f;
#pragma unroll
    for (int k = 0; k < 4; ++k) {
        const int i = t + k * 256;
        sz0 += wsf[WS_PZ + i];        sm0 += wsf[WS_PM + i];
        sz1 += wsf[WS_PZ + 1024 + i]; sm1 += wsf[WS_PM + 1024 + i];
    }
#pragma unroll
    for (int m = 32; m >= 1; m >>= 1) {
        sz0 += __shfl_xor(sz0, m, 64); sm0 += __shfl_xor(sm0, m, 64);
        sz1 += __shfl_xor(sz1, m, 64); sm1 += __shfl_xor(sm1, m, 64);
    }
    if (lane == 0) {
        red[wid * 4 + 0] = sz0; red[wid * 4 + 1] = sm0;
        red[wid * 4 + 2] = sz1; red[wid * 4 + 3] = sm1;
    }
    __syncthreads();
    const float zm0 = (red[0] + red[4] + red[8] + red[12]) /
                      fmaxf(red[1] + red[5] + red[9] + red[13], 1.f);
    const float zm1 = (red[2] + red[6] + red[10] + red[14]) /
                      fmaxf(red[3] + red[7] + red[11] + red[15], 1.f);

    // ---- per-lane folded weights ----
    float w1c[10];
#pragma unroll
    for (int f = 0; f < 10; ++f) w1c[f] = wsf[WS_W1T + c * 10 + f];
    const float b1c = wsf[WS_B1 + c];
    float w2c[C_];
#pragma unroll
    for (int k = 0; k < C_; ++k) w2c[k] = wsf[WS_W2T + c * C_ + k];
    const float b2c = wsf[WS_B2 + c];

    const int W  = blockIdx.x * 4 + wid;
    const int NW = GRID * 4;

    // ---- compute role: occupied cells, 2-deep pipelined chain walk ----
    {
        const int cnt = wsi[WS_CNT];
        for (int e = W; e < cnt; e += NW) {
            const int idx  = wsi[WS_LIST + e];
            const int b    = idx >> 20;
            const int cell = idx & (CELLS - 1);
            const float pxf = (float)(cell & (NX_ - 1));
            const float pyf = (float)(cell >> 10);
            const float zmean = b ? zm1 : zm0;
            const int nb = b * N_;
            float hmax = 0.f;

            // pipeline state: n0 = current (data in x0..r0), n1 = next id
            int n0 = wsi[WS_HEAD + idx];
            int n1 = -1;
            float x0 = 0.f, y0 = 0.f, z0 = 0.f, i0 = 0.f, r0 = 0.f;
            float x1 = 0.f, y1 = 0.f, z1 = 0.f, i1 = 0.f, r1 = 0.f;
            if (n0 != -1) {
                const size_t pb = ((size_t)nb + n0) * 5;
                x0 = pts[pb]; y0 = pts[pb + 1]; z0 = pts[pb + 2];
                i0 = pts[pb + 3]; r0 = pts[pb + 4];
                n1 = wsi[WS_NEXT + nb + n0];
            }
            while (n0 != -1) {
                int n2 = -1;
                if (n1 != -1) {                      // issue next point's loads NOW;
                    n2 = wsi[WS_NEXT + nb + n1];     // consumed only after the full
                    const size_t pb = ((size_t)nb + n1) * 5;   // visit below (~290cy)
                    x1 = pts[pb]; y1 = pts[pb + 1]; z1 = pts[pb + 2];
                    i1 = pts[pb + 3]; r1 = pts[pb + 4];
                }
                // visit point n0 (data already in registers)
                float a = b1c;
                a = fmaf(x0, w1c[0], a);
                a = fmaf(y0, w1c[1], a);
                a = fmaf(z0, w1c[2], a);
                a = fmaf(i0, w1c[3], a);
                a = fmaf(r0, w1c[4], a);
                a = fmaf(x0 - (pxf * VS0 + PC0 + VS0 * 0.5f), w1c[5], a);
                a = fmaf(y0 - (pyf * VS1 + PC1 + VS1 * 0.5f), w1c[6], a);
                a = fmaf(z0 - zmean,                          w1c[7], a);
                a = fmaf(x0 - (pxf * VS0 + PC0),              w1c[8], a);
                a = fmaf(y0 - (pyf * VS1 + PC1),              w1c[9], a);
                const int h1i = __float_as_int(fmaxf(a, 0.f));   // lane k holds h1[k]
                float ac0 = 0.f, ac1 = 0.f, ac2 = 0.f, ac3 = 0.f;
#pragma unroll
                for (int k = 0; k < 16; ++k) {   // same k-order + 4-way split as rounds 2-15
                    ac0 = fmaf(__int_as_float(__builtin_amdgcn_readlane(h1i, 4 * k + 0)), w2c[4 * k + 0], ac0);
                    ac1 = fmaf(__int_as_float(__builtin_amdgcn_readlane(h1i, 4 * k + 1)), w2c[4 * k + 1], ac1);
                    ac2 = fmaf(__int_as_float(__builtin_amdgcn_readlane(h1i, 4 * k + 2)), w2c[4 * k + 2], ac2);
                    ac3 = fmaf(__int_as_float(__builtin_amdgcn_readlane(h1i, 4 * k + 3)), w2c[4 * k + 3], ac3);
                }
                hmax = fmaxf(hmax, b2c + ((ac0 + ac1) + (ac2 + ac3)));
                // shift pipeline
                n0 = n1; n1 = n2;
                x0 = x1; y0 = y1; z0 = z1; i0 = i1; r0 = r1;
            }
            out[(((size_t)b * C_ + c) << 20) + cell] = hmax;
        }
    }

    // ---- zero role: 2048-cell stripes, one bitmap word per lane ----
    {
        f32x4* out4 = (f32x4*)out;
        const f32x4 z4 = {0.f, 0.f, 0.f, 0.f};
        for (int s = W; s < NSTRIPE; s += NW) {
            const int p  = s >> 9;          // plane = b*64 + ch
            const int q  = s & 511;         // stripe within plane (2048 cells)
            const int bb = p >> 6;
            const int Wd = wsi[WS_BMP + bb * (CELLS / 32) + q * 64 + lane];
            const int ib = (p << 18) + (q << 9);   // f32x4 base index of stripe
            if (__ballot(Wd != 0) == 0ULL) {
#pragma unroll
                for (int k = 0; k < 8; ++k)
                    __builtin_nontemporal_store(z4, out4 + (ib + k * 64 + lane));
            } else {
#pragma unroll
                for (int k = 0; k < 8; ++k) {
                    const unsigned w   = (unsigned)__shfl(Wd, k * 8 + (lane >> 3), 64);
                    const unsigned nib = (w >> ((lane & 7) * 4)) & 0xFu;
                    const int i = ib + k * 64 + lane;
                    if (nib == 0u) {
                        __builtin_nontemporal_store(z4, out4 + i);
                    } else {
#pragma unroll
                        for (int jj = 0; jj < 4; ++jj)
                            if (!((nib >> jj) & 1u)) out[(size_t)i * 4 + jj] = 0.f;
                    }
                }
            }
        }
    }
}

// ---------------- fallback path (round-2, atomic scatter) ----------------
__global__ void prep_weights_fb(const float* __restrict__ W1, const float* __restrict__ g1,
                                const float* __restrict__ b1, const float* __restrict__ m1,
                                const float* __restrict__ v1, const float* __restrict__ W2,
                                const float* __restrict__ g2, const float* __restrict__ b2,
                                const float* __restrict__ m2, const float* __restrict__ v2,
                                float* __restrict__ ws) {
    int c = threadIdx.x;
    if (c >= C_) return;
    float s1 = g1[c] / sqrtf(v1[c] + EPS_);
    for (int f = 0; f < 10; ++f) ws[WS_W1T + c * 10 + f] = W1[f * C_ + c] * s1;
    ws[WS_B1 + c] = b1[c] - m1[c] * s1;
    float s2 = g2[c] / sqrtf(v2[c] + EPS_);
    for (int k = 0; k < C_; ++k) ws[WS_W2T + c * C_ + k] = W2[k * C_ + c] * s2;
    ws[WS_B2 + c] = b2[c] - m2[c] * s2;
}

__global__ void zmean_fb1(const float* __restrict__ pts, const int* __restrict__ mask,
                          float* __restrict__ ws) {
    const int b = blockIdx.y, t = threadIdx.x;
    const int n = blockIdx.x * 256 + t;
    float sz = 0.f, sm = 0.f;
    if (n < N_ && mask[b * N_ + n]) {
        sz = pts[((size_t)b * N_ + n) * 5 + 2];
        sm = 1.f;
    }
    __shared__ float lz[256], lm[256];
    lz[t] = sz; lm[t] = sm;
    __syncthreads();
    for (int s = 128; s > 0; s >>= 1) {
        if (t < s) { lz[t] += lz[t + s]; lm[t] += lm[t + s]; }
        __syncthreads();
    }
    if (t == 0) { ws[WS_PZ + b * 1024 + blockIdx.x] = lz[0]; ws[WS_PM + b * 1024 + blockIdx.x] = lm[0]; }
}

__global__ void zmean_fb2(float* __restrict__ ws) {
    const int b = blockIdx.x, t = threadIdx.x;
    __shared__ float lz[256], lm[256];
    float sz = 0.f, sm = 0.f;
    for (int k = t; k < 1024; k += 256) {
        sz += (k < PBLK) ? ws[WS_PZ + b * 1024 + k] : 0.f;
        sm += (k < PBLK) ? ws[WS_PM + b * 1024 + k] : 0.f;
    }
    lz[t] = sz; lm[t] = sm;
    __syncthreads();
    for (int s = 128; s > 0; s >>= 1) {
        if (t < s) { lz[t] += lz[t + s]; lm[t] += lm[t + s]; }
        __syncthreads();
    }
    if (t == 0) ws[WS_CNT + 2 + b] = lz[0] / fmaxf(lm[0], 1.f);  // stash zmean
}

__global__ __launch_bounds__(256) void pfn_scatter_fb(const float* __restrict__ pts,
                                                      const int* __restrict__ mask,
                                                      const float* __restrict__ ws,
                                                      float* __restrict__ out) {
    const int b = blockIdx.y;
    const int n = blockIdx.x * 256 + threadIdx.x;
    if (n >= N_) return;
    if (!mask[b * N_ + n]) return;
    const float zmean = ws[WS_CNT + 2 + b];
    const size_t pbase = ((size_t)b * N_ + n) * 5;
    const float x = pts[pbase], y = pts[pbase + 1], z = pts[pbase + 2];
    const float it = pts[pbase + 3], rg = pts[pbase + 4];
    const int cell = cell_of(x, y);
    const float pxf = (float)(cell & (NX_ - 1)), pyf = (float)(cell >> 10);
    float aug[10];
    aug[0] = x; aug[1] = y; aug[2] = z; aug[3] = it; aug[4] = rg;
    aug[5] = x - (pxf * VS0 + PC0 + VS0 * 0.5f);
    aug[6] = y - (pyf * VS1 + PC1 + VS1 * 0.5f);
    aug[7] = z - zmean;
    aug[8] = x - (pxf * VS0 + PC0);
    aug[9] = y - (pyf * VS1 + PC1);
    float h1[C_];
#pragma unroll
    for (int c = 0; c < C_; ++c) {
        float acc = ws[WS_B1 + c];
#pragma unroll
        for (int f = 0; f < 10; ++f) acc = fmaf(aug[f], ws[WS_W1T + c * 10 + f], acc);
        h1[c] = fmaxf(acc, 0.f);
    }
    unsigned int* ob = (unsigned int*)out + (size_t)b * C_ * CELLS + cell;
#pragma unroll 4
    for (int c = 0; c < C_; ++c) {
        float acc = ws[WS_B2 + c];
#pragma unroll
        for (int k = 0; k < C_; ++k) acc = fmaf(h1[k], ws[WS_W2T + c * C_ + k], acc);
        if (acc > 0.f) atomicMax(ob + (size_t)c * CELLS, __float_as_uint(acc));
    }
}

extern "C" void kernel_launch(void* const* d_in, const int* in_sizes, int n_in,
                              void* d_out, int out_size, void* d_ws, size_t ws_size,
                              hipStream_t stream) {
    const float* pts  = (const float*)d_in[0];
    const int*   mask = (const int*)d_in[1];
    const float* W1 = (const float*)d_in[2];
    const float* g1 = (const float*)d_in[3];
    const float* b1 = (const float*)d_in[4];
    const float* m1 = (const float*)d_in[5];
    const float* v1 = (const float*)d_in[6];
    const float* W2 = (const float*)d_in[7];
    const float* g2 = (const float*)d_in[8];
    const float* b2 = (const float*)d_in[9];
    const float* m2 = (const float*)d_in[10];
    const float* v2 = (const float*)d_in[11];
    float* wsf = (float*)d_ws;
    int*   wsi = (int*)d_ws;
    float* out = (float*)d_out;

    if (ws_size >= NEED_BYTES) {
        init_prep<<<512, 256, 0, stream>>>(W1, g1, b1, m1, v1, W2, g2, b2, m2, v2, wsf, wsi);
        pass1<<<dim3(PBLK, B_), 256, 0, stream>>>(pts, mask, wsf, wsi);
        fat<<<GRID, 256, 0, stream>>>(pts, wsf, wsi, out);
    } else {
        hipMemsetAsync(d_out, 0, (size_t)out_size * sizeof(float), stream);
        hipMemsetAsync((char*)d_ws + (size_t)WS_PZ * 4, 0, 4096 * 4, stream);
        prep_weights_fb<<<1, 256, 0, stream>>>(W1, g1, b1, m1, v1, W2, g2, b2, m2, v2, wsf);
        zmean_fb1<<<dim3(PBLK, B_), 256, 0, stream>>>(pts, mask, wsf);
        zmean_fb2<<<B_, 256, 0, stream>>>(wsf);
        pfn_scatter_fb<<<dim3((N_ + 255) / 256, B_), 256, 0, stream>>>(pts, mask, wsf, out);
    }
}